// Round 11
// baseline (563.214 us; speedup 1.0000x reference)
//
#include <hip/hip_runtime.h>
#include <hip/hip_bf16.h>
#include <stdint.h>

// ---------------------------------------------------------------------------
// QuantGRU: T=512, B=64, I=256, H=256. ACT scale 2^-7, W scale 2^-8.
// Fully exact integer arithmetic; sigmoid/tanh via 256-entry f64-built LUTs.
// Recurrence (R11): STREAMING design. R5-R10 proved the allocator never keeps
// weight arrays in VGPRs across the t-loop (and v_dot4 can't read AGPRs), so
// weights are explicitly re-loaded from L2 every step (k-chunk-transposed =>
// coalesced 1KB wave-loads, issued at loop top to hide under the readlane
// chain). 512 thr = 8 waves = 2/SIMD for latency overlap: threads 0-255 own
// the z+g column pair (gate tail fully local except ri), threads 256-511 own
// r and publish ri=lutS[ar] pre-barrier. Two light lgkm-only barriers/step.
// ---------------------------------------------------------------------------

#define T_STEPS 512
#define BATCH   64
#define IDIM    256
#define HDIM    256
#define N3H     768   // 3*H

#if defined(__has_builtin)
#if __has_builtin(__builtin_amdgcn_sdot4)
#define DOT4(a,b,c) __builtin_amdgcn_sdot4((int)(a),(int)(b),(int)(c),false)
#endif
#endif
#ifndef DOT4
__device__ __forceinline__ int dot4_sw(uint32_t a, uint32_t b, int c){
  c += (int)(int8_t)(a)      * (int)(int8_t)(b);
  c += (int)(int8_t)(a>>8)   * (int)(int8_t)(b>>8);
  c += (int)(int8_t)(a>>16)  * (int)(int8_t)(b>>16);
  c += (int)(int8_t)(a>>24)  * (int)(int8_t)(b>>24);
  return c;
}
#define DOT4(a,b,c) dot4_sw((uint32_t)(a),(uint32_t)(b),(int)(c))
#endif

// select dword component of a uint4 by compile-time constant
#define CHUNK(W,c) (((c)&3)==0 ? W[(c)>>2].x : ((c)&3)==1 ? W[(c)>>2].y : \
                    ((c)&3)==2 ? W[(c)>>2].z : W[(c)>>2].w)

// LDS-only workgroup barrier (no vmcnt drain; loads/stores stay in flight)
__device__ __forceinline__ void barrier_lds() {
  asm volatile("s_waitcnt lgkmcnt(0)\n\ts_barrier" ::: "memory");
}

// ---- exact integer round-to-nearest-even helpers (verified vs jnp.round) ---
__device__ __forceinline__ int clamp8(int x)   { return min(127, max(-128, x)); }
__device__ __forceinline__ int rne_half(int y) { int t = y >> 1; return t + (t & y & 1); }
__device__ __forceinline__ int rne_s8(int s)   { return (s + 127 + ((s >> 8) & 1)) >> 8; }
__device__ __forceinline__ int rne_s7(int p)   { return (p + 63 + ((p >> 7) & 1)) >> 7; }

// float RNE+clamp (quantize; used in prep/gemm only)
__device__ __forceinline__ int rneclamp(float v) {
  int q = (int)rintf(v);
  return min(127, max(-128, q));
}

__device__ __forceinline__ uint32_t packq4(float4 f, float sc) {
  uint32_t b0 = (uint32_t)(uint8_t)(int8_t)rneclamp(f.x * sc);
  uint32_t b1 = (uint32_t)(uint8_t)(int8_t)rneclamp(f.y * sc);
  uint32_t b2 = (uint32_t)(uint8_t)(int8_t)rneclamp(f.z * sc);
  uint32_t b3 = (uint32_t)(uint8_t)(int8_t)rneclamp(f.w * sc);
  return b0 | (b1 << 8) | (b2 << 16) | (b3 << 24);
}

// ---------------------------------------------------------------------------
// prep: W AND R -> k-chunk-transposed int8 (uint4 #kk of column j sits at
// ((uint4*)X)[kk*768 + j] => lane-consecutive j = coalesced 1KB wave loads).
// ---------------------------------------------------------------------------
__global__ void prep_kernel(const float* __restrict__ W, const float* __restrict__ R,
                            const float* __restrict__ bx, const float* __restrict__ br,
                            int8_t* __restrict__ Wq, int8_t* __restrict__ Rq,
                            int8_t* __restrict__ bx8, int8_t* __restrict__ br8) {
  const int NW = IDIM * N3H; // 196608
  int idx = blockIdx.x * 256 + threadIdx.x;
  if (idx < NW) {
    int k = idx / N3H, j = idx % N3H;
    Wq[((size_t)(k >> 4) * N3H + j) * 16 + (k & 15)] = (int8_t)rneclamp(W[idx] * 256.0f);
  } else if (idx < 2 * NW) {
    int i2 = idx - NW;
    int k = i2 / N3H, j = i2 % N3H;
    Rq[((size_t)(k >> 4) * N3H + j) * 16 + (k & 15)] = (int8_t)rneclamp(R[i2] * 256.0f);
  } else if (idx < 2 * NW + N3H) {
    int i2 = idx - 2 * NW;
    bx8[i2] = (int8_t)rneclamp(bx[i2] * 256.0f);
  } else if (idx < 2 * NW + 2 * N3H) {
    int i2 = idx - 2 * NW - N3H;
    br8[i2] = (int8_t)rneclamp(br[i2] * 256.0f);
  }
}

// ---------------------------------------------------------------------------
// gemm_wx: Wx_q[b][t][j] = clamp(rne( (fq(x) . Wq col j) / 256 ))  (int8)
// one block per t (64 rows), 768 threads = one per output column.
// ---------------------------------------------------------------------------
__global__ __launch_bounds__(768, 1) void gemm_wx_kernel(
    const float* __restrict__ x, const int8_t* __restrict__ Wq,
    int8_t* __restrict__ WxQ8) {
  const int t = blockIdx.x;   // 0..511
  const int j = threadIdx.x;  // 0..767

  __shared__ uint4 xq4[64 * 16];   // 64 rows x 256 int8 = 16KB
  uint32_t* xq = (uint32_t*)xq4;

  uint4 w[16];
  const uint4* wp = (const uint4*)Wq;
  #pragma unroll
  for (int kk = 0; kk < 16; ++kk) w[kk] = wp[kk * N3H + j];

  const float4* xg = (const float4*)(x) + (size_t)t * 4096;
  for (int i = j; i < 4096; i += 768) {
    float4 f = xg[i];
    xq[i] = packq4(f, 128.0f);
  }
  __syncthreads();

  for (int r = 0; r < 64; ++r) {
    int s = 0;
    #pragma unroll
    for (int kk = 0; kk < 16; ++kk) {
      uint4 hv = xq4[r * 16 + kk];
      s = DOT4(hv.x, w[kk].x, s);
      s = DOT4(hv.y, w[kk].y, s);
      s = DOT4(hv.z, w[kk].z, s);
      s = DOT4(hv.w, w[kk].w, s);
    }
    int q = clamp8(rne_s8(s));
    WxQ8[((size_t)r * T_STEPS + t) * N3H + j] = (int8_t)q;
  }
}

// ---------------------------------------------------------------------------
// gru_rec11: one block per batch; 512 threads = 8 waves (2/SIMD).
//   threads 0-255  (zg role): cols j and j+512 -> vz,vg,zi local; gate tail;
//                             h state; out store; hq publish.
//   threads 256-511 (r role): col j+256 -> ri = lutS[ar] -> LDS pre-barrier.
// Weights streamed from L2 every step (loads issued at loop top).
// ---------------------------------------------------------------------------
__global__ __launch_bounds__(512, 1)
void gru_rec11_kernel(
    const float* __restrict__ h0, const int8_t* __restrict__ Rq,
    const int8_t* __restrict__ bx8, const int8_t* __restrict__ br8,
    const int8_t* __restrict__ WxQ8, float* __restrict__ out) {
  const int b = blockIdx.x;     // batch element
  const int tid = threadIdx.x;  // 0..511
  const int j = tid & 255;
  const int lane = tid & 63;

  __shared__ uint32_t hq[2][64];    // double-buffered int8 h (256 B each)
  __shared__ int rbuf[256];         // ri published by r role
  __shared__ int8_t lutS[256];
  __shared__ int8_t lutT[256];

  const uint4* rp = (const uint4*)Rq;

  // prologue: LUTs (f64) + initial h
  int hi = 0;
  if (tid < 256) {
    double a = ((double)j - 128.0) / 128.0;
    lutS[j] = (int8_t)min(127, max(-128, (int)rint(128.0 / (1.0 + exp(-a)))));
    hi = (int)rintf(h0[b * HDIM + j] * 128.0f);   // exact int, units 1/128
    ((int8_t*)&hq[0][0])[j] = (int8_t)clamp8(hi);
  } else {
    double a = ((double)j - 128.0) / 128.0;
    lutT[j] = (int8_t)min(127, max(-128, (int)rint(128.0 * tanh(a))));
  }
  __syncthreads();

  if (tid < 256) {
    // ===================== zg role =====================
    const int bzc = (int)bx8[j];
    const int vbz = (int)br8[j];
    const int bgc = (int)bx8[j + 512];
    const int vbg = (int)br8[j + 512];
    const int8_t* wxp = WxQ8 + (size_t)b * T_STEPS * N3H + j;
    float* outp = out + (size_t)b * HDIM + j;
    // 2-deep Wx prefetch (z and g lanes of the step)
    int zA = (int)wxp[0],   gA = (int)wxp[512];
    int zB = (int)wxp[N3H], gB = (int)wxp[N3H + 512];

    for (int t = 0; t < T_STEPS; ++t) {
      const int cur = t & 1, nxt = cur ^ 1;
      // stream this step's weights (L2-resident; coalesced 1KB wave loads)
      uint4 wz[16], wg[16];
      #pragma unroll
      for (int kk = 0; kk < 16; ++kk) {
        wz[kk] = rp[kk * N3H + j];
        wg[kk] = rp[kk * N3H + 512 + j];
      }
      // Wx prefetch t+2
      const int8_t* p = wxp + (size_t)min(t + 2, T_STEPS - 1) * N3H;
      int zn = (int)p[0], gn = (int)p[512];

      // GEMV: h broadcast via readlane -> SGPR; dot4 both columns
      uint32_t hw = hq[cur][lane];
      int sz = 0, sg = 0;
      #pragma unroll
      for (int c = 0; c < 64; ++c) {
        int hc = __builtin_amdgcn_readlane((int)hw, c);
        sz = DOT4(hc, CHUNK(wz, c), sz);
        sg = DOT4(hc, CHUNK(wg, c), sg);
      }
      int vz = clamp8(rne_half(2 * clamp8(rne_s8(sz)) + vbz));
      int vg = clamp8(rne_half(2 * clamp8(rne_s8(sg)) + vbg));
      int az = clamp8(rne_half(2 * (zA + vz) + bzc));
      int zi = (int)lutS[az + 128];          // gather issued pre-barrier

      barrier_lds();   // #1: rbuf ready
      int ri = rbuf[j];
      int rrh = clamp8(rne_s7(ri * vg));
      int ag = clamp8(rne_half(2 * (gA + rrh) + bgc));
      int gi = (int)lutT[ag + 128];
      int oldi = clamp8(rne_s7(zi * hi));
      int newi = clamp8(rne_s7((128 - zi) * gi));
      hi = oldi + newi;                       // integer, units 1/128
      outp[(size_t)t * BATCH * HDIM] = (float)hi * (1.0f / 128.0f);
      ((int8_t*)&hq[nxt][0])[j] = (int8_t)clamp8(hi);
      zA = zB; gA = gB; zB = zn; gB = gn;
      barrier_lds();   // #2: hq[nxt] published
    }
  } else {
    // ===================== r role =====================
    const int brc = (int)bx8[j + 256];
    const int vbr = (int)br8[j + 256];
    const int8_t* wxp = WxQ8 + (size_t)b * T_STEPS * N3H + 256 + j;
    int rA = (int)wxp[0], rB = (int)wxp[N3H];

    for (int t = 0; t < T_STEPS; ++t) {
      const int cur = t & 1;
      uint4 wr[16];
      #pragma unroll
      for (int kk = 0; kk < 16; ++kk) wr[kk] = rp[kk * N3H + 256 + j];
      const int8_t* p = wxp + (size_t)min(t + 2, T_STEPS - 1) * N3H;
      int rn = (int)p[0];

      uint32_t hw = hq[cur][lane];
      int sr = 0;
      #pragma unroll
      for (int c = 0; c < 64; ++c) {
        int hc = __builtin_amdgcn_readlane((int)hw, c);
        sr = DOT4(hc, CHUNK(wr, c), sr);
      }
      int vr = clamp8(rne_half(2 * clamp8(rne_s8(sr)) + vbr));
      int ar = clamp8(rne_half(2 * (rA + vr) + brc));
      rbuf[j] = (int)lutS[ar + 128];
      rA = rB; rB = rn;
      barrier_lds();   // #1
      barrier_lds();   // #2
    }
  }
}

// ---------------------------------------------------------------------------
extern "C" void kernel_launch(void* const* d_in, const int* in_sizes, int n_in,
                              void* d_out, int out_size, void* d_ws, size_t ws_size,
                              hipStream_t stream) {
  const float* x  = (const float*)d_in[0];   // (T,B,I)
  const float* h0 = (const float*)d_in[1];   // (B,H)
  const float* W  = (const float*)d_in[2];   // (I,3H)
  const float* R  = (const float*)d_in[3];   // (H,3H)
  const float* bx = (const float*)d_in[4];   // (3H,)
  const float* br = (const float*)d_in[5];   // (3H,)
  float* out = (float*)d_out;                // (T,B,H)

  // workspace layout
  const size_t NW = (size_t)IDIM * N3H;          // 196608
  int8_t* Wq  = (int8_t*)d_ws;                   // 196608
  int8_t* Rq  = Wq + NW;                         // 196608
  int8_t* bx8 = Rq + NW;                         // 768
  int8_t* br8 = bx8 + N3H;                       // 768
  int8_t* WxQ8 = br8 + N3H;                      // 64*512*768 = 25165824

  {
    int total = (int)(2 * NW + 2 * N3H);
    int blocks = (total + 255) / 256;
    prep_kernel<<<blocks, 256, 0, stream>>>(W, R, bx, br, Wq, Rq, bx8, br8);
  }
  gemm_wx_kernel<<<T_STEPS, 768, 0, stream>>>(x, Wq, WxQ8);
  gru_rec11_kernel<<<BATCH, 512, 0, stream>>>(h0, Rq, bx8, br8, WxQ8, out);
}

// Round 12
// 460.048 us; speedup vs baseline: 1.2243x; 1.2243x over previous
//
#include <hip/hip_runtime.h>
#include <hip/hip_bf16.h>
#include <stdint.h>

// ---------------------------------------------------------------------------
// QuantGRU: T=512, B=64, I=256, H=256. ACT scale 2^-7, W scale 2^-8.
// Fully exact integer arithmetic; gate nonlinearities via fused LDS LUTs
// built in f64 (compositions of the exact integer ops -- bit-identical).
// R12: R6 skeleton (1 block/batch, 256 thr, thread j owns gate triple) with
//  (a) h-broadcast via wave-uniform ds_read_b128 (no readlane/SGPR hazards),
//  (b) fused LUTs: lutS2 (index-fused sigmoid), lutT2 (index-fused tanh),
//      lutRR 64KB 2D (ar,vg)->rrh (kills the ri gather + mul chain).
// ---------------------------------------------------------------------------

#define T_STEPS 512
#define BATCH   64
#define IDIM    256
#define HDIM    256
#define N3H     768   // 3*H

#if defined(__has_builtin)
#if __has_builtin(__builtin_amdgcn_sdot4)
#define DOT4(a,b,c) __builtin_amdgcn_sdot4((int)(a),(int)(b),(int)(c),false)
#endif
#endif
#ifndef DOT4
__device__ __forceinline__ int dot4_sw(uint32_t a, uint32_t b, int c){
  c += (int)(int8_t)(a)      * (int)(int8_t)(b);
  c += (int)(int8_t)(a>>8)   * (int)(int8_t)(b>>8);
  c += (int)(int8_t)(a>>16)  * (int)(int8_t)(b>>16);
  c += (int)(int8_t)(a>>24)  * (int)(int8_t)(b>>24);
  return c;
}
#define DOT4(a,b,c) dot4_sw((uint32_t)(a),(uint32_t)(b),(int)(c))
#endif

// LDS-only workgroup barrier (no vmcnt drain; loads/stores stay in flight)
__device__ __forceinline__ void barrier_lds() {
  asm volatile("s_waitcnt lgkmcnt(0)\n\ts_barrier" ::: "memory");
}

// ---- exact integer round-to-nearest-even helpers (verified vs jnp.round) ---
__device__ __forceinline__ int clamp8(int x)   { return min(127, max(-128, x)); }
__device__ __forceinline__ int rne_half(int y) { int t = y >> 1; return t + (t & y & 1); }
__device__ __forceinline__ int rne_s8(int s)   { return (s + 127 + ((s >> 8) & 1)) >> 8; }
__device__ __forceinline__ int rne_s7(int p)   { return (p + 63 + ((p >> 7) & 1)) >> 7; }

// float RNE+clamp (quantize; used in prep/gemm only)
__device__ __forceinline__ int rneclamp(float v) {
  int q = (int)rintf(v);
  return min(127, max(-128, q));
}

__device__ __forceinline__ uint32_t packq4(float4 f, float sc) {
  uint32_t b0 = (uint32_t)(uint8_t)(int8_t)rneclamp(f.x * sc);
  uint32_t b1 = (uint32_t)(uint8_t)(int8_t)rneclamp(f.y * sc);
  uint32_t b2 = (uint32_t)(uint8_t)(int8_t)rneclamp(f.z * sc);
  uint32_t b3 = (uint32_t)(uint8_t)(int8_t)rneclamp(f.w * sc);
  return b0 | (b1 << 8) | (b2 << 16) | (b3 << 24);
}

// ---------------------------------------------------------------------------
// prep: W -> k-chunk-transposed int8 (for gemm_wx coalesced column loads),
// R -> plain column-major int8, biases -> int8.
// ---------------------------------------------------------------------------
__global__ void prep_kernel(const float* __restrict__ W, const float* __restrict__ R,
                            const float* __restrict__ bx, const float* __restrict__ br,
                            int8_t* __restrict__ Wq, int8_t* __restrict__ Rq,
                            int8_t* __restrict__ bx8, int8_t* __restrict__ br8) {
  const int NW = IDIM * N3H; // 196608
  int idx = blockIdx.x * 256 + threadIdx.x;
  if (idx < NW) {
    int k = idx / N3H, j = idx % N3H;
    Wq[((size_t)(k >> 4) * N3H + j) * 16 + (k & 15)] = (int8_t)rneclamp(W[idx] * 256.0f);
  } else if (idx < 2 * NW) {
    int i2 = idx - NW;
    int k = i2 / N3H, j = i2 % N3H;
    Rq[(size_t)j * HDIM + k] = (int8_t)rneclamp(R[i2] * 256.0f);   // col-major
  } else if (idx < 2 * NW + N3H) {
    int i2 = idx - 2 * NW;
    bx8[i2] = (int8_t)rneclamp(bx[i2] * 256.0f);
  } else if (idx < 2 * NW + 2 * N3H) {
    int i2 = idx - 2 * NW - N3H;
    br8[i2] = (int8_t)rneclamp(br[i2] * 256.0f);
  }
}

// ---------------------------------------------------------------------------
// gemm_wx: Wx_q[b][t][j] = clamp(rne( (fq(x) . Wq col j) / 256 ))  (int8)
// one block per t (64 rows), 768 threads = one per output column.
// ---------------------------------------------------------------------------
__global__ __launch_bounds__(768, 1) void gemm_wx_kernel(
    const float* __restrict__ x, const int8_t* __restrict__ Wq,
    int8_t* __restrict__ WxQ8) {
  const int t = blockIdx.x;   // 0..511
  const int j = threadIdx.x;  // 0..767

  __shared__ uint4 xq4[64 * 16];   // 64 rows x 256 int8 = 16KB
  uint32_t* xq = (uint32_t*)xq4;

  uint4 w[16];
  const uint4* wp = (const uint4*)Wq;
  #pragma unroll
  for (int kk = 0; kk < 16; ++kk) w[kk] = wp[kk * N3H + j];

  const float4* xg = (const float4*)(x) + (size_t)t * 4096;
  for (int i = j; i < 4096; i += 768) {
    float4 f = xg[i];
    xq[i] = packq4(f, 128.0f);
  }
  __syncthreads();

  for (int r = 0; r < 64; ++r) {
    int s = 0;
    #pragma unroll
    for (int kk = 0; kk < 16; ++kk) {
      uint4 hv = xq4[r * 16 + kk];
      s = DOT4(hv.x, w[kk].x, s);
      s = DOT4(hv.y, w[kk].y, s);
      s = DOT4(hv.z, w[kk].z, s);
      s = DOT4(hv.w, w[kk].w, s);
    }
    int q = clamp8(rne_s8(s));
    WxQ8[((size_t)r * T_STEPS + t) * N3H + j] = (int8_t)q;
  }
}

// ---------------------------------------------------------------------------
// gru_rec12: one block per batch; 256 threads (4 waves), thread j owns h[j]
// and its gate triple. Dynamic LDS:
//   [0, 65536)          lutRR  : rrh = f(ar, vg)      (2D fused)
//   [65536, 67584)      lutS2  : zi  = f(2*(wz+vz)+bz) (index-fused sigmoid)
//   [67584, 69632)      lutT2  : gi  = f(2*(wg+rrh)+bg) (index-fused tanh)
//   [69632, 70144)      hq     : 2 x 16 uint4 double-buffered int8 h
// ---------------------------------------------------------------------------
__global__ __launch_bounds__(256, 1)
void gru_rec12_kernel(
    const float* __restrict__ h0, const int8_t* __restrict__ Rq,
    const int8_t* __restrict__ bx8, const int8_t* __restrict__ br8,
    const int8_t* __restrict__ WxQ8, float* __restrict__ out) {
  const int b = blockIdx.x;     // batch element
  const int j = threadIdx.x;    // 0..255

  extern __shared__ int8_t smem[];
  int8_t*  lutRR = smem;                      // 65536
  int8_t*  lutS2 = smem + 65536;              // 2048
  int8_t*  lutT2 = smem + 67584;              // 2048
  uint4*   hqb   = (uint4*)(smem + 69632);    // 2*16 uint4

  // R columns j, j+256, j+512 (as in R6; allocator handles residency)
  uint4 wz[16], wr[16], wg[16];
  {
    const uint4* pz = (const uint4*)(Rq + (size_t)j * HDIM);
    const uint4* pr = (const uint4*)(Rq + (size_t)(j + 256) * HDIM);
    const uint4* pg = (const uint4*)(Rq + (size_t)(j + 512) * HDIM);
    #pragma unroll
    for (int kk = 0; kk < 16; ++kk) { wz[kk] = pz[kk]; wr[kk] = pr[kk]; wg[kk] = pg[kk]; }
  }
  const int bzc = (int)bx8[j];
  const int brc = (int)bx8[j + 256];
  const int bgc = (int)bx8[j + 512];
  const int vbz = (int)br8[j];
  const int vbr = (int)br8[j + 256];
  const int vbg = (int)br8[j + 512];

  // ---- build fused LUTs in f64 (exact compositions of the integer ops) ----
  {
    const double inv128 = 1.0 / 128.0;
    #pragma unroll
    for (int i = 0; i < 8; ++i) {
      int y = j * 8 + i - 1024;
      int v = clamp8(rne_half(y));
      lutS2[j * 8 + i] = (int8_t)clamp8((int)rint(128.0 / (1.0 + exp(-(double)v * inv128))));
      lutT2[j * 8 + i] = (int8_t)clamp8((int)rint(128.0 * tanh((double)v * inv128)));
    }
    // row ar+128 == j of lutRR: ri = lutS[j], entries over vg
    int ri = clamp8((int)rint(128.0 / (1.0 + exp(-((double)j - 128.0) * inv128))));
    uint32_t* rrw = (uint32_t*)lutRR;
    for (int v4 = 0; v4 < 64; ++v4) {
      uint32_t w = 0;
      #pragma unroll
      for (int e = 0; e < 4; ++e) {
        int v = v4 * 4 + e - 128;
        int rr = clamp8(rne_s7(ri * v));
        w |= ((uint32_t)(uint8_t)(int8_t)rr) << (8 * e);
      }
      rrw[j * 64 + v4] = w;
    }
  }
  // h carried as exact integer hi (units 1/128)
  int hi = (int)rintf(h0[b * HDIM + j] * 128.0f);
  ((int8_t*)&hqb[0])[j] = (int8_t)clamp8(hi);
  __syncthreads();

  const int8_t* wxp = WxQ8 + (size_t)b * T_STEPS * N3H + j;
  float* outp = out + (size_t)b * HDIM + j;

  // Wx 2-deep prefetch pipeline: A = step t, B = step t+1
  int wxA0 = (int)wxp[0],   wxA1 = (int)wxp[256],       wxA2 = (int)wxp[512];
  int wxB0 = (int)wxp[N3H], wxB1 = (int)wxp[N3H + 256], wxB2 = (int)wxp[N3H + 512];

  for (int t = 0; t < T_STEPS; ++t) {
    const int cur = t & 1, nxt = cur ^ 1;

    // issue Wx loads for t+2 first (~2 steps of latency hiding)
    const int8_t* p = wxp + (size_t)min(t + 2, T_STEPS - 1) * N3H;
    int nz = (int)p[0], nr = (int)p[256], ng = (int)p[512];

    // ---- GEMV: h via wave-uniform ds_read_b128 broadcasts, dot4 vgpr x vgpr
    const uint4* hc = &hqb[cur * 16];
    int sz = 0, sr = 0, sg = 0;
    #pragma unroll
    for (int kk = 0; kk < 16; ++kk) {
      uint4 hv = hc[kk];
      sz = DOT4(hv.x, wz[kk].x, sz);
      sr = DOT4(hv.x, wr[kk].x, sr);
      sg = DOT4(hv.x, wg[kk].x, sg);
      sz = DOT4(hv.y, wz[kk].y, sz);
      sr = DOT4(hv.y, wr[kk].y, sr);
      sg = DOT4(hv.y, wg[kk].y, sg);
      sz = DOT4(hv.z, wz[kk].z, sz);
      sr = DOT4(hv.z, wr[kk].z, sr);
      sg = DOT4(hv.z, wg[kk].z, sg);
      sz = DOT4(hv.w, wz[kk].w, sz);
      sr = DOT4(hv.w, wr[kk].w, sr);
      sg = DOT4(hv.w, wg[kk].w, sg);
    }
    // v = fq(fq(s/2^15,7)+br,7)  -- all integer, exact
    int vz = clamp8(rne_half(2 * clamp8(rne_s8(sz)) + vbz));
    int vr = clamp8(rne_half(2 * clamp8(rne_s8(sr)) + vbr));
    int vg = clamp8(rne_half(2 * clamp8(rne_s8(sg)) + vbg));

    // gates via fused LUTs (exact)
    int zi  = (int)lutS2[2 * (wxA0 + vz) + bzc + 1024];          // parallel path
    int ar  = clamp8(rne_half(2 * (wxA1 + vr) + brc));
    int rrh = (int)lutRR[((ar + 128) << 8) | (vg + 128)];        // fused ri*vg
    int gi  = (int)lutT2[2 * (wxA2 + rrh) + bgc + 1024];
    int oldi = clamp8(rne_s7(zi * hi));
    int newi = clamp8(rne_s7((128 - zi) * gi));
    hi = oldi + newi;                       // integer, units 1/128
    outp[(size_t)t * BATCH * HDIM] = (float)hi * (1.0f / 128.0f);
    ((int8_t*)&hqb[nxt * 16])[j] = (int8_t)clamp8(hi);

    // advance Wx pipeline
    wxA0 = wxB0; wxA1 = wxB1; wxA2 = wxB2;
    wxB0 = nz;   wxB1 = nr;   wxB2 = ng;

    barrier_lds();   // LDS-only: hq[nxt] visible; vmcnt stays in flight
  }
}

// ---------------------------------------------------------------------------
extern "C" void kernel_launch(void* const* d_in, const int* in_sizes, int n_in,
                              void* d_out, int out_size, void* d_ws, size_t ws_size,
                              hipStream_t stream) {
  const float* x  = (const float*)d_in[0];   // (T,B,I)
  const float* h0 = (const float*)d_in[1];   // (B,H)
  const float* W  = (const float*)d_in[2];   // (I,3H)
  const float* R  = (const float*)d_in[3];   // (H,3H)
  const float* bx = (const float*)d_in[4];   // (3H,)
  const float* br = (const float*)d_in[5];   // (3H,)
  float* out = (float*)d_out;                // (T,B,H)

  // workspace layout
  const size_t NW = (size_t)IDIM * N3H;          // 196608
  int8_t* Wq  = (int8_t*)d_ws;                   // 196608
  int8_t* Rq  = Wq + NW;                         // 196608
  int8_t* bx8 = Rq + NW;                         // 768
  int8_t* br8 = bx8 + N3H;                       // 768
  int8_t* WxQ8 = br8 + N3H;                      // 64*512*768 = 25165824

  {
    int total = (int)(2 * NW + 2 * N3H);
    int blocks = (total + 255) / 256;
    prep_kernel<<<blocks, 256, 0, stream>>>(W, R, bx, br, Wq, Rq, bx8, br8);
  }
  gemm_wx_kernel<<<T_STEPS, 768, 0, stream>>>(x, Wq, WxQ8);
  gru_rec12_kernel<<<BATCH, 256, 70144, stream>>>(h0, Rq, bx8, br8, WxQ8, out);
}